// Round 3
// baseline (246.399 us; speedup 1.0000x reference)
//
#include <hip/hip_runtime.h>
#include <hip/hip_bf16.h>
#include <stdint.h>

typedef __hip_bfloat16 bf16;
typedef unsigned short u16;
typedef __attribute__((ext_vector_type(8))) short short8;
typedef __attribute__((ext_vector_type(4))) float f32x4;

#define BATCH 8
#define SEQ   1024
#define DIM   1024
#define NHEAD 16
#define HD    64
#define SCALE 0.03125f               // DIM^-0.5 = 1/32 (exact)
#define NEGMAX (-3.402823466e38f)

static __device__ __forceinline__ f32x4 mfma_bf16(short8 a, short8 b, f32x4 c) {
    return __builtin_amdgcn_mfma_f32_16x16x32_bf16(a, b, c, 0, 0, 0);
}

// ---------------------------------------------------------------------------
// Detect input dtypes from bit patterns (deterministic given inputs).
// flags[0] = 1 if float tensors are f32 on device (else bf16-packed)
// flags[1] = 1 if mask is byte-packed bool (else int32)
// ---------------------------------------------------------------------------
__global__ __launch_bounds__(256)
void detect_flags(const uint32_t* __restrict__ xw, const uint32_t* __restrict__ mw,
                  int* __restrict__ flags)
{
    __shared__ int cnt_bf16, cnt_gt1;
    if (threadIdx.x == 0) { cnt_bf16 = 0; cnt_gt1 = 0; }
    __syncthreads();
    const uint32_t w = xw[threadIdx.x];
    const int e = (int)((w >> 7) & 0xFFu);
    if (e >= 96 && e <= 159) atomicAdd(&cnt_bf16, 1);
    const uint32_t m = mw[threadIdx.x];
    if (m > 1u) atomicAdd(&cnt_gt1, 1);
    __syncthreads();
    if (threadIdx.x == 0) {
        flags[0] = (cnt_bf16 >= 192) ? 0 : 1;
        flags[1] = (cnt_gt1 > 0) ? 1 : 0;
    }
}

// ---------------------------------------------------------------------------
// Convert a float tensor (f32 or packed bf16, per flag) to canonical bf16.
// ---------------------------------------------------------------------------
__global__ __launch_bounds__(256)
void convert_to_bf16(const void* __restrict__ src, u16* __restrict__ dst, int n,
                     const int* __restrict__ flags)
{
    const bool f32in = (flags[0] != 0);
    const int total = n >> 3;
    for (int i = blockIdx.x * blockDim.x + threadIdx.x; i < total;
         i += gridDim.x * blockDim.x) {
        if (f32in) {
            const float4 a = ((const float4*)src)[2 * i];
            const float4 b = ((const float4*)src)[2 * i + 1];
            short8 o;
            o[0] = (short)__builtin_bit_cast(u16, __float2bfloat16(a.x));
            o[1] = (short)__builtin_bit_cast(u16, __float2bfloat16(a.y));
            o[2] = (short)__builtin_bit_cast(u16, __float2bfloat16(a.z));
            o[3] = (short)__builtin_bit_cast(u16, __float2bfloat16(a.w));
            o[4] = (short)__builtin_bit_cast(u16, __float2bfloat16(b.x));
            o[5] = (short)__builtin_bit_cast(u16, __float2bfloat16(b.y));
            o[6] = (short)__builtin_bit_cast(u16, __float2bfloat16(b.z));
            o[7] = (short)__builtin_bit_cast(u16, __float2bfloat16(b.w));
            ((short8*)dst)[i] = o;
        } else {
            ((short8*)dst)[i] = ((const short8*)src)[i];
        }
    }
}

// mlx[b][0] = 1 (pad-true), mlx[b][i] = mask[b][i-1]
__global__ __launch_bounds__(1024)
void expand_mask(const void* __restrict__ mask, int* __restrict__ mlx,
                 const int* __restrict__ flags)
{
    const int b = blockIdx.x, i = threadIdx.x;
    int v;
    if (i == 0) v = 1;
    else if (flags[1]) v = (int)((const uint8_t*)mask)[b * (SEQ - 1) + i - 1];
    else               v = ((const int*)mask)[b * (SEQ - 1) + i - 1];
    mlx[b * SEQ + i] = v ? 1 : 0;
}

// ---------------------------------------------------------------------------
// GEMM: C[i][j] = sum_k A[i][k] * B[j][k]   (A @ B^T), K = 1024, bf16 in.
// grid = (M/128, N/128), 256 threads = 4 waves (2x2), each wave 64x64 out.
// EPI 0: scatter C into q/k/v [B][H][SEQ][HD] bf16.
// EPI 1: C + bias -> fo as f32 [M][DIM]  (d_out is float per out_npz size).
// ---------------------------------------------------------------------------
template<int EPI>
__global__ __launch_bounds__(256)
void gemm_bt(const u16* __restrict__ A, const u16* __restrict__ Bm,
             bf16* __restrict__ o0, bf16* __restrict__ o1, bf16* __restrict__ o2,
             float* __restrict__ fo, const u16* __restrict__ bias)
{
    constexpr int K   = 1024;
    constexpr int LDT = 40;                 // 32 + 8 pad
    __shared__ u16 lA[2][128 * LDT];
    __shared__ u16 lB[2][128 * LDT];

    const int tid  = threadIdx.x;
    const int lane = tid & 63;
    const int w    = tid >> 6;
    const int wr   = w >> 1, wc = w & 1;
    const int l15  = lane & 15, l4 = lane >> 4;

    const int srow = tid >> 2;
    const int sc8  = tid & 3;

    const long arow = (long)blockIdx.x * 128 + srow;
    const long brow = (long)blockIdx.y * 128 + srow;

    f32x4 acc[4][4];
    const f32x4 fz = {0.f, 0.f, 0.f, 0.f};
#pragma unroll
    for (int i = 0; i < 4; ++i)
#pragma unroll
        for (int j = 0; j < 4; ++j) acc[i][j] = fz;

    short8 ra0 = *(const short8*)(A + arow * K + sc8 * 8);
    short8 ra1 = *(const short8*)(A + (arow + 64) * K + sc8 * 8);
    short8 rb0 = *(const short8*)(Bm + brow * K + sc8 * 8);
    short8 rb1 = *(const short8*)(Bm + (brow + 64) * K + sc8 * 8);
    *(short8*)&lA[0][srow * LDT + sc8 * 8]        = ra0;
    *(short8*)&lA[0][(srow + 64) * LDT + sc8 * 8] = ra1;
    *(short8*)&lB[0][srow * LDT + sc8 * 8]        = rb0;
    *(short8*)&lB[0][(srow + 64) * LDT + sc8 * 8] = rb1;

    int cur = 0;
    constexpr int NT = K / 32;
#pragma unroll 2
    for (int kt = 0; kt < NT; ++kt) {
        __syncthreads();
        if (kt + 1 < NT) {                  // T14: issue next-tile loads early
            const int off = (kt + 1) * 32;
            ra0 = *(const short8*)(A + arow * K + off + sc8 * 8);
            ra1 = *(const short8*)(A + (arow + 64) * K + off + sc8 * 8);
            rb0 = *(const short8*)(Bm + brow * K + off + sc8 * 8);
            rb1 = *(const short8*)(Bm + (brow + 64) * K + off + sc8 * 8);
        }
        short8 af[4], bfr[4];
#pragma unroll
        for (int mt = 0; mt < 4; ++mt)
            af[mt] = *(const short8*)&lA[cur][(wr * 64 + mt * 16 + l15) * LDT + l4 * 8];
#pragma unroll
        for (int nt = 0; nt < 4; ++nt)
            bfr[nt] = *(const short8*)&lB[cur][(wc * 64 + nt * 16 + l15) * LDT + l4 * 8];
#pragma unroll
        for (int mt = 0; mt < 4; ++mt)
#pragma unroll
            for (int nt = 0; nt < 4; ++nt)
                acc[mt][nt] = mfma_bf16(af[mt], bfr[nt], acc[mt][nt]);
        if (kt + 1 < NT) {                  // write-late into other buffer
            const int nb = cur ^ 1;
            *(short8*)&lA[nb][srow * LDT + sc8 * 8]        = ra0;
            *(short8*)&lA[nb][(srow + 64) * LDT + sc8 * 8] = ra1;
            *(short8*)&lB[nb][srow * LDT + sc8 * 8]        = rb0;
            *(short8*)&lB[nb][(srow + 64) * LDT + sc8 * 8] = rb1;
            cur = nb;
        }
    }

    // epilogue: C/D layout col = lane&15, row = (lane>>4)*4 + r  [m89/m91]
    const long ci0 = (long)blockIdx.x * 128 + wr * 64;
    const int  cj0 = blockIdx.y * 128 + wc * 64;
#pragma unroll
    for (int mt = 0; mt < 4; ++mt) {
#pragma unroll
        for (int nt = 0; nt < 4; ++nt) {
            const int j = cj0 + nt * 16 + l15;
#pragma unroll
            for (int r = 0; r < 4; ++r) {
                const long i = ci0 + mt * 16 + l4 * 4 + r;
                float vv = acc[mt][nt][r];
                if (EPI == 0) {
                    const int which = j >> 10;         // 0=q 1=k 2=v
                    const int h     = (j >> 6) & 15;
                    const int dd    = j & 63;
                    const long b    = i >> 10;
                    const long n    = i & 1023;
                    bf16* dst = (which == 0) ? o0 : ((which == 1) ? o1 : o2);
                    dst[((b * NHEAD + h) * SEQ + n) * HD + dd] = __float2bfloat16(vv);
                } else {
                    const u16 bw = bias[j];
                    vv += __bfloat162float(__builtin_bit_cast(bf16, bw));
                    fo[i * DIM + j] = vv;              // f32 output
                }
            }
        }
    }
}

// ---------------------------------------------------------------------------
// Flash attention: block = (b,h) x 64 Q-rows; 4 waves x 16 rows. KV tiles 64.
// ---------------------------------------------------------------------------
__global__ __launch_bounds__(256)
void attn_fwd(const bf16* __restrict__ q, const bf16* __restrict__ k,
              const bf16* __restrict__ v, const int* __restrict__ mlx,
              bf16* __restrict__ o)
{
    __shared__ u16 kl[64 * 72];        // K tile, row-major, +8 pad
    __shared__ u16 vt[64 * 72];        // V^T tile [dd][j], XOR-swizzled cols
    __shared__ u16 pl[4][16 * 72];     // per-wave P
    __shared__ int ml[SEQ];

    const int tid  = threadIdx.x;
    const int lane = tid & 63;
    const int w    = tid >> 6;
    const int l15  = lane & 15, l4 = lane >> 4;
    const int bh   = blockIdx.x >> 4;  // b*16 + h
    const int qt   = blockIdx.x & 15;
    const int b    = bh >> 4;

    for (int i = tid; i < SEQ; i += 256) ml[i] = mlx[b * SEQ + i];

    const long base = (long)bh * SEQ * HD;

    const int qrow = qt * 64 + w * 16 + l15;
    const short8 qf0 = *(const short8*)(q + base + (long)qrow * HD + l4 * 8);
    const short8 qf1 = *(const short8*)(q + base + (long)qrow * HD + 32 + l4 * 8);

    __syncthreads();                   // ml ready
    int mi[4];
#pragma unroll
    for (int r = 0; r < 4; ++r) mi[r] = ml[qt * 64 + w * 16 + l4 * 4 + r];

    float mrun[4], lrun[4];
    f32x4 oacc[4];
    const f32x4 fz = {0.f, 0.f, 0.f, 0.f};
#pragma unroll
    for (int r = 0; r < 4; ++r) { mrun[r] = -__builtin_inff(); lrun[r] = 0.f; }
#pragma unroll
    for (int ot = 0; ot < 4; ++ot) oacc[ot] = fz;

    const int sr = tid >> 3;
    const int sc = tid & 7;

    short8 rk0 = *(const short8*)(k + base + (long)sr * HD + sc * 8);
    short8 rk1 = *(const short8*)(k + base + (long)(sr + 32) * HD + sc * 8);
    short8 rv0 = *(const short8*)(v + base + (long)sr * HD + sc * 8);
    short8 rv1 = *(const short8*)(v + base + (long)(sr + 32) * HD + sc * 8);

#pragma unroll 1
    for (int t = 0; t < 16; ++t) {
        __syncthreads();               // all waves done with previous tile
        *(short8*)&kl[sr * 72 + sc * 8]        = rk0;
        *(short8*)&kl[(sr + 32) * 72 + sc * 8] = rk1;
#pragma unroll
        for (int e = 0; e < 8; ++e) {  // V transpose; col XOR-swizzle
            const int dd = sc * 8 + e;
            vt[dd * 72 + (sr ^ (sc * 8))]        = (u16)rv0[e];
            vt[dd * 72 + ((sr + 32) ^ (sc * 8))] = (u16)rv1[e];
        }
        if (t < 15) {                  // prefetch next KV tile
            const long nb2 = base + (long)(t + 1) * 64 * HD;
            rk0 = *(const short8*)(k + nb2 + (long)sr * HD + sc * 8);
            rk1 = *(const short8*)(k + nb2 + (long)(sr + 32) * HD + sc * 8);
            rv0 = *(const short8*)(v + nb2 + (long)sr * HD + sc * 8);
            rv1 = *(const short8*)(v + nb2 + (long)(sr + 32) * HD + sc * 8);
        }
        __syncthreads();               // tile staged

        const int kv0 = t * 64;
        f32x4 s[4];
#pragma unroll
        for (int jt = 0; jt < 4; ++jt) {
            const short8 kf0 = *(const short8*)&kl[(jt * 16 + l15) * 72 + l4 * 8];
            const short8 kf1 = *(const short8*)&kl[(jt * 16 + l15) * 72 + 32 + l4 * 8];
            f32x4 z = fz;
            z = mfma_bf16(qf0, kf0, z);
            z = mfma_bf16(qf1, kf1, z);
            s[jt] = z;
        }
#pragma unroll
        for (int jt = 0; jt < 4; ++jt) {
            const int mj = ml[kv0 + jt * 16 + l15];
#pragma unroll
            for (int r = 0; r < 4; ++r) {
                const float sv = s[jt][r] * SCALE;
                s[jt][r] = (mi[r] && mj) ? sv : NEGMAX;
            }
        }
        float mloc[4], rs[4];
#pragma unroll
        for (int r = 0; r < 4; ++r)
            mloc[r] = fmaxf(fmaxf(s[0][r], s[1][r]), fmaxf(s[2][r], s[3][r]));
#pragma unroll
        for (int d2 = 1; d2 < 16; d2 <<= 1)
#pragma unroll
            for (int r = 0; r < 4; ++r)
                mloc[r] = fmaxf(mloc[r], __shfl_xor(mloc[r], d2));
        float fac[4];
#pragma unroll
        for (int r = 0; r < 4; ++r) {
            const float mn = fmaxf(mrun[r], mloc[r]);
            fac[r]  = __expf(mrun[r] - mn);   // exp(-inf)=0 on first tile
            mrun[r] = mn;
            rs[r]   = 0.f;
        }
#pragma unroll
        for (int jt = 0; jt < 4; ++jt)
#pragma unroll
            for (int r = 0; r < 4; ++r) {
                const float p = __expf(s[jt][r] - mrun[r]);
                s[jt][r] = p;
                rs[r] += p;
            }
#pragma unroll
        for (int d2 = 1; d2 < 16; d2 <<= 1)
#pragma unroll
            for (int r = 0; r < 4; ++r) rs[r] += __shfl_xor(rs[r], d2);
#pragma unroll
        for (int r = 0; r < 4; ++r) lrun[r] = lrun[r] * fac[r] + rs[r];
#pragma unroll
        for (int ot = 0; ot < 4; ++ot)
#pragma unroll
            for (int r = 0; r < 4; ++r) oacc[ot][r] *= fac[r];
#pragma unroll
        for (int jt = 0; jt < 4; ++jt)
#pragma unroll
            for (int r = 0; r < 4; ++r) {
                const bf16 hb = __float2bfloat16(s[jt][r]);
                pl[w][(l4 * 4 + r) * 72 + jt * 16 + l15] = __builtin_bit_cast(u16, hb);
            }
        asm volatile("s_waitcnt lgkmcnt(0)" ::: "memory");  // wave-local P RAW
        __builtin_amdgcn_sched_barrier(0);                  // rule #18 fence
#pragma unroll
        for (int ks = 0; ks < 2; ++ks) {
            const short8 pf = *(const short8*)&pl[w][l15 * 72 + ks * 32 + l4 * 8];
#pragma unroll
            for (int ot = 0; ot < 4; ++ot) {
                const int dd = ot * 16 + l15;
                const int jb = (ks * 32 + l4 * 8) ^ ((dd >> 3) * 8);
                const short8 vf = *(const short8*)&vt[dd * 72 + jb];
                oacc[ot] = mfma_bf16(pf, vf, oacc[ot]);
            }
        }
    }

#pragma unroll
    for (int ot = 0; ot < 4; ++ot)
#pragma unroll
        for (int r = 0; r < 4; ++r) {
            const int n = qt * 64 + w * 16 + l4 * 4 + r;
            const float val = oacc[ot][r] / lrun[r];
            o[((long)(b * SEQ + n)) * DIM + (bh & 15) * HD + ot * 16 + l15] =
                __float2bfloat16(val);
        }
}

// ---------------------------------------------------------------------------
extern "C" void kernel_launch(void* const* d_in, const int* in_sizes, int n_in,
                              void* d_out, int out_size, void* d_ws, size_t ws_size,
                              hipStream_t stream)
{
    (void)in_sizes; (void)n_in; (void)out_size; (void)ws_size;
    const void* x    = d_in[0];
    const void* mask = d_in[1];
    const void* Wqkv = d_in[2];
    const void* Wout = d_in[3];
    const void* bout = d_in[4];
    float* out = (float*)d_out;                           // f32 per out_npz size

    const size_t nX = (size_t)BATCH * SEQ * DIM;          // 8,388,608
    const size_t nWqkv = (size_t)3 * DIM * DIM;           // 3,145,728
    const size_t nWout = (size_t)DIM * DIM;               // 1,048,576
    const size_t nBout = DIM;                             // 1,024
    const size_t per   = (size_t)BATCH * NHEAD * SEQ * HD;// 8,388,608

    char* wp = (char*)d_ws;
    int* flags = (int*)wp;                 wp += 256;
    u16* xb    = (u16*)wp;                 wp += nX * 2;   // also reused as ab
    u16* Wqkvb = (u16*)wp;                 wp += nWqkv * 2;
    u16* Woutb = (u16*)wp;                 wp += nWout * 2;
    u16* boutb = (u16*)wp;                 wp += nBout * 2;
    int* mlx   = (int*)wp;                 wp += BATCH * SEQ * 4;
    u16* qb    = (u16*)wp;                 wp += per * 2;
    u16* kb    = (u16*)wp;                 wp += per * 2;
    u16* vb    = (u16*)wp;                 wp += per * 2;

    detect_flags<<<1, 256, 0, stream>>>((const uint32_t*)x, (const uint32_t*)mask, flags);
    convert_to_bf16<<<2048, 256, 0, stream>>>(x,    xb,    (int)nX,    flags);
    convert_to_bf16<<<1536, 256, 0, stream>>>(Wqkv, Wqkvb, (int)nWqkv, flags);
    convert_to_bf16<<<512,  256, 0, stream>>>(Wout, Woutb, (int)nWout, flags);
    convert_to_bf16<<<1,    256, 0, stream>>>(bout, boutb, (int)nBout, flags);
    expand_mask<<<BATCH, 1024, 0, stream>>>(mask, mlx, flags);

    // qkv = x @ Wqkv^T : M=8192, N=3072
    gemm_bt<0><<<dim3(64, 24), 256, 0, stream>>>(xb, Wqkvb,
        (bf16*)qb, (bf16*)kb, (bf16*)vb, nullptr, nullptr);
    // attention -> ab (reuses xb region; x no longer needed)
    bf16* ab = (bf16*)xb;
    attn_fwd<<<dim3(BATCH * NHEAD * (SEQ / 64)), 256, 0, stream>>>(
        (const bf16*)qb, (const bf16*)kb, (const bf16*)vb, mlx, ab);
    // out = attn @ Wout^T + bout : M=8192, N=1024 (f32 out)
    gemm_bt<1><<<dim3(64, 8), 256, 0, stream>>>((const u16*)ab, Woutb,
        nullptr, nullptr, nullptr, out, boutb);
}

// Round 5
// 223.826 us; speedup vs baseline: 1.1009x; 1.1009x over previous
//
#include <hip/hip_runtime.h>
#include <hip/hip_bf16.h>
#include <stdint.h>

typedef __hip_bfloat16 bf16;
typedef unsigned short u16;
typedef __attribute__((ext_vector_type(8))) short short8;
typedef __attribute__((ext_vector_type(4))) float f32x4;
typedef __attribute__((ext_vector_type(16))) float f32x16;
typedef __attribute__((ext_vector_type(4))) int int4v;

#define BATCH 8
#define SEQ   1024
#define DIM   1024
#define NHEAD 16
#define HD    64
#define SCALE 0.03125f               // DIM^-0.5 = 1/32 (exact)
#define C2    0.04508422f            // SCALE * log2(e)

static __device__ __forceinline__ f32x4 mfma_bf16(short8 a, short8 b, f32x4 c) {
    return __builtin_amdgcn_mfma_f32_16x16x32_bf16(a, b, c, 0, 0, 0);
}
static __device__ __forceinline__ f32x16 mfma32(short8 a, short8 b, f32x16 c) {
    return __builtin_amdgcn_mfma_f32_32x32x16_bf16(a, b, c, 0, 0, 0);
}
static __device__ __forceinline__ unsigned cvt_pk_bf16(float lo, float hi) {
    unsigned r;
    asm("v_cvt_pk_bf16_f32 %0, %1, %2" : "=v"(r) : "v"(lo), "v"(hi));
    return r;
}
static __device__ __forceinline__ float readlane_f(float v, int l) {
    return __builtin_bit_cast(float,
        __builtin_amdgcn_readlane(__builtin_bit_cast(int, v), l));
}

// ---------------------------------------------------------------------------
// Dtype detection (bit-pattern based, deterministic).
// ---------------------------------------------------------------------------
__global__ __launch_bounds__(256)
void detect_flags(const uint32_t* __restrict__ xw, const uint32_t* __restrict__ mw,
                  int* __restrict__ flags)
{
    __shared__ int cnt_bf16, cnt_gt1;
    if (threadIdx.x == 0) { cnt_bf16 = 0; cnt_gt1 = 0; }
    __syncthreads();
    const uint32_t w = xw[threadIdx.x];
    const int e = (int)((w >> 7) & 0xFFu);
    if (e >= 96 && e <= 159) atomicAdd(&cnt_bf16, 1);
    const uint32_t m = mw[threadIdx.x];
    if (m > 1u) atomicAdd(&cnt_gt1, 1);
    __syncthreads();
    if (threadIdx.x == 0) {
        flags[0] = (cnt_bf16 >= 192) ? 0 : 1;
        flags[1] = (cnt_gt1 > 0) ? 1 : 0;
    }
}

__global__ __launch_bounds__(256)
void convert_to_bf16(const void* __restrict__ src, u16* __restrict__ dst, int n,
                     const int* __restrict__ flags)
{
    const bool f32in = (flags[0] != 0);
    const int total = n >> 3;
    for (int i = blockIdx.x * blockDim.x + threadIdx.x; i < total;
         i += gridDim.x * blockDim.x) {
        if (f32in) {
            const float4 a = ((const float4*)src)[2 * i];
            const float4 b = ((const float4*)src)[2 * i + 1];
            short8 o;
            o[0] = (short)__builtin_bit_cast(u16, __float2bfloat16(a.x));
            o[1] = (short)__builtin_bit_cast(u16, __float2bfloat16(a.y));
            o[2] = (short)__builtin_bit_cast(u16, __float2bfloat16(a.z));
            o[3] = (short)__builtin_bit_cast(u16, __float2bfloat16(a.w));
            o[4] = (short)__builtin_bit_cast(u16, __float2bfloat16(b.x));
            o[5] = (short)__builtin_bit_cast(u16, __float2bfloat16(b.y));
            o[6] = (short)__builtin_bit_cast(u16, __float2bfloat16(b.z));
            o[7] = (short)__builtin_bit_cast(u16, __float2bfloat16(b.w));
            ((short8*)dst)[i] = o;
        } else {
            ((short8*)dst)[i] = ((const short8*)src)[i];
        }
    }
}

// mlx[b][0]=1 (pad-true), mlx[b][i]=mask[b][i-1]; mask64[b][t] = 64-bit tile mask
__global__ __launch_bounds__(1024)
void expand_mask(const void* __restrict__ mask, int* __restrict__ mlx,
                 unsigned long long* __restrict__ mask64,
                 const int* __restrict__ flags)
{
    const int b = blockIdx.x, i = threadIdx.x;
    int v;
    if (i == 0) v = 1;
    else if (flags[1]) v = (int)((const uint8_t*)mask)[b * (SEQ - 1) + i - 1];
    else               v = ((const int*)mask)[b * (SEQ - 1) + i - 1];
    v = v ? 1 : 0;
    mlx[b * SEQ + i] = v;
    const unsigned long long bal = __ballot(v);
    if ((i & 63) == 0) mask64[b * 16 + (i >> 6)] = bal;
}

// ---------------------------------------------------------------------------
// GEMM: C = A @ B^T, K=1024, bf16. 4 waves (2x2), wave 64x64.
// EPI 0: scatter into q/k [bh][n][64] and V TRANSPOSED [bh][d][n].
// EPI 1: C + bias -> f32 [M][DIM].
// ---------------------------------------------------------------------------
template<int EPI>
__global__ __launch_bounds__(256)
void gemm_bt(const u16* __restrict__ A, const u16* __restrict__ Bm,
             bf16* __restrict__ o0, bf16* __restrict__ o1, bf16* __restrict__ o2,
             float* __restrict__ fo, const u16* __restrict__ bias)
{
    constexpr int K   = 1024;
    constexpr int LDT = 40;
    __shared__ u16 lA[2][128 * LDT];
    __shared__ u16 lB[2][128 * LDT];

    const int tid  = threadIdx.x;
    const int lane = tid & 63;
    const int w    = tid >> 6;
    const int wr   = w >> 1, wc = w & 1;
    const int l15  = lane & 15, l4 = lane >> 4;
    const int srow = tid >> 2;
    const int sc8  = tid & 3;

    const long arow = (long)blockIdx.x * 128 + srow;
    const long brow = (long)blockIdx.y * 128 + srow;

    f32x4 acc[4][4];
    const f32x4 fz = {0.f, 0.f, 0.f, 0.f};
#pragma unroll
    for (int i = 0; i < 4; ++i)
#pragma unroll
        for (int j = 0; j < 4; ++j) acc[i][j] = fz;

    short8 ra0 = *(const short8*)(A + arow * K + sc8 * 8);
    short8 ra1 = *(const short8*)(A + (arow + 64) * K + sc8 * 8);
    short8 rb0 = *(const short8*)(Bm + brow * K + sc8 * 8);
    short8 rb1 = *(const short8*)(Bm + (brow + 64) * K + sc8 * 8);
    *(short8*)&lA[0][srow * LDT + sc8 * 8]        = ra0;
    *(short8*)&lA[0][(srow + 64) * LDT + sc8 * 8] = ra1;
    *(short8*)&lB[0][srow * LDT + sc8 * 8]        = rb0;
    *(short8*)&lB[0][(srow + 64) * LDT + sc8 * 8] = rb1;

    int cur = 0;
    constexpr int NT = K / 32;
#pragma unroll 2
    for (int kt = 0; kt < NT; ++kt) {
        __syncthreads();
        if (kt + 1 < NT) {
            const int off = (kt + 1) * 32;
            ra0 = *(const short8*)(A + arow * K + off + sc8 * 8);
            ra1 = *(const short8*)(A + (arow + 64) * K + off + sc8 * 8);
            rb0 = *(const short8*)(Bm + brow * K + off + sc8 * 8);
            rb1 = *(const short8*)(Bm + (brow + 64) * K + off + sc8 * 8);
        }
        short8 af[4], bfr[4];
#pragma unroll
        for (int mt = 0; mt < 4; ++mt)
            af[mt] = *(const short8*)&lA[cur][(wr * 64 + mt * 16 + l15) * LDT + l4 * 8];
#pragma unroll
        for (int nt = 0; nt < 4; ++nt)
            bfr[nt] = *(const short8*)&lB[cur][(wc * 64 + nt * 16 + l15) * LDT + l4 * 8];
#pragma unroll
        for (int mt = 0; mt < 4; ++mt)
#pragma unroll
            for (int nt = 0; nt < 4; ++nt)
                acc[mt][nt] = mfma_bf16(af[mt], bfr[nt], acc[mt][nt]);
        if (kt + 1 < NT) {
            const int nb = cur ^ 1;
            *(short8*)&lA[nb][srow * LDT + sc8 * 8]        = ra0;
            *(short8*)&lA[nb][(srow + 64) * LDT + sc8 * 8] = ra1;
            *(short8*)&lB[nb][srow * LDT + sc8 * 8]        = rb0;
            *(short8*)&lB[nb][(srow + 64) * LDT + sc8 * 8] = rb1;
            cur = nb;
        }
    }

    const long ci0 = (long)blockIdx.x * 128 + wr * 64;
    const int  cj0 = blockIdx.y * 128 + wc * 64;
#pragma unroll
    for (int mt = 0; mt < 4; ++mt) {
#pragma unroll
        for (int nt = 0; nt < 4; ++nt) {
            const int j = cj0 + nt * 16 + l15;
#pragma unroll
            for (int r = 0; r < 4; ++r) {
                const long i = ci0 + mt * 16 + l4 * 4 + r;
                float vv = acc[mt][nt][r];
                if (EPI == 0) {
                    const int which = j >> 10;         // 0=q 1=k 2=v
                    const int h     = (j >> 6) & 15;
                    const int dd    = j & 63;
                    const long b    = i >> 10;
                    const long n    = i & 1023;
                    const long bhh  = b * NHEAD + h;
                    if (which == 0)
                        o0[(bhh * SEQ + n) * HD + dd] = __float2bfloat16(vv);
                    else if (which == 1)
                        o1[(bhh * SEQ + n) * HD + dd] = __float2bfloat16(vv);
                    else // V stored transposed: [bh][d][n]
                        o2[(bhh * HD + dd) * SEQ + n] = __float2bfloat16(vv);
                } else {
                    const u16 bw = bias[j];
                    vv += __bfloat162float(__builtin_bit_cast(bf16, bw));
                    fo[i * DIM + j] = vv;
                }
            }
        }
    }
}

// ---------------------------------------------------------------------------
// Flash attention, swapped-operand 32x32 form (m214 structure).
// Block = (b,h) x 128 q-rows; 4 waves x 32 q. KV tiles of 64.
// S^T = mfma(K, Q^T): lane owns q = lane&31; 32 k-values in regs.
// V is pre-transposed in global ([bh][d][n]) -> contiguous B-frags from LDS.
// ---------------------------------------------------------------------------
__global__ __launch_bounds__(256)
void attn_fwd(const bf16* __restrict__ q, const bf16* __restrict__ k,
              const bf16* __restrict__ vt_g, const int* __restrict__ mlx,
              const unsigned long long* __restrict__ mask64,
              bf16* __restrict__ o)
{
    __shared__ u16 kl[64 * 72];        // K tile  [k in tile][d], +8 pad
    __shared__ u16 vl[64 * 72];        // V^T tile [d][k in tile], +8 pad

    const int tid  = threadIdx.x;
    const int lane = tid & 63;
    const int w    = tid >> 6;
    const int l31  = lane & 31;
    const int hi   = lane >> 5;
    const int bh   = blockIdx.x >> 3;
    const int qt   = blockIdx.x & 7;
    const int b    = bh >> 4;
    const int h    = bh & 15;

    const long base  = (long)bh * SEQ * HD;   // q,k: [bh][n][64]
    const long vbase = (long)bh * HD * SEQ;   // v^T: [bh][d][1024]

    const int qrow = qt * 128 + w * 32 + l31;

    short8 qf[4];                      // Q[qrow][s4*16 + hi*8 .. +7]
#pragma unroll
    for (int s4 = 0; s4 < 4; ++s4)
        qf[s4] = *(const short8*)(q + base + (long)qrow * HD + s4 * 16 + hi * 8);

    const int mi = mlx[b * SEQ + qrow];
    float mrun = mi ? -1e30f : 0.0f;
    float lrun = 0.0f;
    f32x16 oacc0, oacc1;
#pragma unroll
    for (int i = 0; i < 16; ++i) { oacc0[i] = 0.f; oacc1[i] = 0.f; }

    // staging: 256 threads, 2 x b128 each per tile (K and V^T)
    const int sr = tid >> 2, sc = tid & 3;
    short8 rk0 = *(const short8*)(k + base + (long)sr * HD + sc * 8);
    short8 rk1 = *(const short8*)(k + base + (long)sr * HD + 32 + sc * 8);
    short8 rv0 = *(const short8*)(vt_g + vbase + (long)sr * SEQ + sc * 8);
    short8 rv1 = *(const short8*)(vt_g + vbase + (long)sr * SEQ + 32 + sc * 8);

#pragma unroll 1
    for (int t = 0; t < 16; ++t) {
        __syncthreads();
        *(short8*)&kl[sr * 72 + sc * 8]      = rk0;
        *(short8*)&kl[sr * 72 + 32 + sc * 8] = rk1;
        *(short8*)&vl[sr * 72 + sc * 8]      = rv0;
        *(short8*)&vl[sr * 72 + 32 + sc * 8] = rv1;
        if (t < 15) {                  // T14: issue next-tile loads early
            const long kn = base + (long)((t + 1) * 64 + sr) * HD;
            rk0 = *(const short8*)(k + kn + sc * 8);
            rk1 = *(const short8*)(k + kn + 32 + sc * 8);
            const long vn = vbase + (long)sr * SEQ + (t + 1) * 64;
            rv0 = *(const short8*)(vt_g + vn + sc * 8);
            rv1 = *(const short8*)(vt_g + vn + 32 + sc * 8);
        }
        __syncthreads();

        // S^T = K . Q^T  (rows k, cols q)
        f32x16 s0, s1;
#pragma unroll
        for (int i = 0; i < 16; ++i) { s0[i] = 0.f; s1[i] = 0.f; }
#pragma unroll
        for (int s4 = 0; s4 < 4; ++s4) {
            const short8 kf0 = *(const short8*)&kl[l31 * 72 + s4 * 16 + hi * 8];
            const short8 kf1 = *(const short8*)&kl[(32 + l31) * 72 + s4 * 16 + hi * 8];
            s0 = mfma32(kf0, qf[s4], s0);
            s1 = mfma32(kf1, qf[s4], s1);
        }

        // row max (raw domain; masked entries only tighten mrun harmlessly)
        float pm = s0[0];
#pragma unroll
        for (int i = 1; i < 16; ++i) pm = fmaxf(pm, s0[i]);
#pragma unroll
        for (int i = 0; i < 16; ++i) pm = fmaxf(pm, s1[i]);
        pm = fmaxf(pm, __shfl_xor(pm, 32));
        if (!mi) pm = -1e30f;

        if (__any(pm > mrun + 64.0f)) {   // T13 defer-max, THR=64 raw (e^2.88 cap)
            const float mnew = fmaxf(mrun, pm);
            const float fac  = exp2f((mrun - mnew) * C2);
            lrun *= fac;
            mrun  = mnew;
            // fac lives at lane==q; accumulator rows need per-row fac
#pragma unroll
            for (int g = 0; g < 4; ++g)
#pragma unroll
                for (int j = 0; j < 4; ++j) {
                    const float f0 = readlane_f(fac, g * 8 + j);
                    const float f1 = readlane_f(fac, g * 8 + j + 4);
                    const float fv = hi ? f1 : f0;
                    oacc0[g * 4 + j] *= fv;
                    oacc1[g * 4 + j] *= fv;
                }
        }

        const float mb = mrun * C2;
        const unsigned long long mk = mask64[b * 16 + t];
        const uint32_t bk0 = (uint32_t)(mk >> (4 * hi));
        const uint32_t bk1 = (uint32_t)(mk >> (32 + 4 * hi));
        float rs = 0.0f;
#pragma unroll
        for (int i = 0; i < 16; ++i) {
            const int c = (i & 3) + 8 * (i >> 2);      // krow - 4*hi
            float p0 = exp2f(__builtin_fmaf(s0[i], C2, -mb));
            float p1 = exp2f(__builtin_fmaf(s1[i], C2, -mb));
            p0 = ((bk0 >> c) & 1u) ? p0 : 0.0f;
            p1 = ((bk1 >> c) & 1u) ? p1 : 0.0f;
            p0 = mi ? p0 : 1.0f;       // fully-masked row -> uniform
            p1 = mi ? p1 : 1.0f;
            s0[i] = p0; s1[i] = p1;
            rs += p0 + p1;
        }
        rs += __shfl_xor(rs, 32);
        lrun += rs;

        // P -> bf16 A-frags: pack lane-local pairs FIRST, then permlane32_swap
        // routes halves (m214 recipe: swap(pk01,pk45)->word0,word2;
        // swap(pk23,pk67)->word1,word3).
#pragma unroll
        for (int kt = 0; kt < 2; ++kt) {
            const f32x16* sp = kt ? &s1 : &s0;
#pragma unroll
            for (int ks = 0; ks < 2; ++ks) {
                unsigned w0 = cvt_pk_bf16((*sp)[8 * ks + 0], (*sp)[8 * ks + 1]);
                unsigned w1 = cvt_pk_bf16((*sp)[8 * ks + 2], (*sp)[8 * ks + 3]);
                unsigned w2 = cvt_pk_bf16((*sp)[8 * ks + 4], (*sp)[8 * ks + 5]);
                unsigned w3 = cvt_pk_bf16((*sp)[8 * ks + 6], (*sp)[8 * ks + 7]);
                asm volatile("v_permlane32_swap_b32 %0, %1" : "+v"(w0), "+v"(w2));
                asm volatile("v_permlane32_swap_b32 %0, %1" : "+v"(w1), "+v"(w3));
                const short8 pa = __builtin_bit_cast(short8,
                    (int4v){(int)w0, (int)w1, (int)w2, (int)w3});
                const int koff = kt * 32 + ks * 16 + hi * 8;
                const short8 vf0 = *(const short8*)&vl[l31 * 72 + koff];
                const short8 vf1 = *(const short8*)&vl[(32 + l31) * 72 + koff];
                oacc0 = mfma32(pa, vf0, oacc0);
                oacc1 = mfma32(pa, vf1, oacc1);
            }
        }
    }

    // epilogue: O[q][d] / l   (l lives at lane==q; broadcast via readlane)
    const float linv = 1.0f / lrun;
#pragma unroll
    for (int g = 0; g < 4; ++g)
#pragma unroll
        for (int j = 0; j < 4; ++j) {
            const float f0 = readlane_f(linv, g * 8 + j);
            const float f1 = readlane_f(linv, g * 8 + j + 4);
            const float lv = hi ? f1 : f0;
            const int qg = qt * 128 + w * 32 + g * 8 + j + 4 * hi;
            const long oaddr = ((long)(b * SEQ + qg)) * DIM + h * HD;
            o[oaddr + l31]      = __float2bfloat16(oacc0[g * 4 + j] * lv);
            o[oaddr + 32 + l31] = __float2bfloat16(oacc1[g * 4 + j] * lv);
        }
}

// ---------------------------------------------------------------------------
extern "C" void kernel_launch(void* const* d_in, const int* in_sizes, int n_in,
                              void* d_out, int out_size, void* d_ws, size_t ws_size,
                              hipStream_t stream)
{
    (void)in_sizes; (void)n_in; (void)out_size; (void)ws_size;
    const void* x    = d_in[0];
    const void* mask = d_in[1];
    const void* Wqkv = d_in[2];
    const void* Wout = d_in[3];
    const void* bout = d_in[4];
    float* out = (float*)d_out;

    const size_t nX    = (size_t)BATCH * SEQ * DIM;
    const size_t nWqkv = (size_t)3 * DIM * DIM;
    const size_t nWout = (size_t)DIM * DIM;
    const size_t nBout = DIM;
    const size_t per   = (size_t)BATCH * NHEAD * SEQ * HD;

    char* wp = (char*)d_ws;
    int* flags = (int*)wp;                      wp += 256;
    u16* xb    = (u16*)wp;                      wp += nX * 2;   // reused as ab
    u16* Wqkvb = (u16*)wp;                      wp += nWqkv * 2;
    u16* Woutb = (u16*)wp;                      wp += nWout * 2;
    u16* boutb = (u16*)wp;                      wp += nBout * 2;
    int* mlx   = (int*)wp;                      wp += BATCH * SEQ * 4;
    unsigned long long* m64 = (unsigned long long*)wp; wp += BATCH * 16 * 8;
    u16* qb    = (u16*)wp;                      wp += per * 2;
    u16* kb    = (u16*)wp;                      wp += per * 2;
    u16* vb    = (u16*)wp;                      wp += per * 2;

    detect_flags<<<1, 256, 0, stream>>>((const uint32_t*)x, (const uint32_t*)mask, flags);
    convert_to_bf16<<<2048, 256, 0, stream>>>(x,    xb,    (int)nX,    flags);
    convert_to_bf16<<<1536, 256, 0, stream>>>(Wqkv, Wqkvb, (int)nWqkv, flags);
    convert_to_bf16<<<512,  256, 0, stream>>>(Wout, Woutb, (int)nWout, flags);
    convert_to_bf16<<<1,    256, 0, stream>>>(bout, boutb, (int)nBout, flags);
    expand_mask<<<BATCH, 1024, 0, stream>>>(mask, mlx, m64, flags);

    // qkv = x @ Wqkv^T : M=8192, N=3072 (V scattered transposed)
    gemm_bt<0><<<dim3(64, 24), 256, 0, stream>>>(xb, Wqkvb,
        (bf16*)qb, (bf16*)kb, (bf16*)vb, nullptr, nullptr);
    // attention -> ab (reuses xb region)
    bf16* ab = (bf16*)xb;
    attn_fwd<<<dim3(BATCH * NHEAD * 8), 256, 0, stream>>>(
        (const bf16*)qb, (const bf16*)kb, (const bf16*)vb, mlx, m64, ab);
    // out = attn @ Wout^T + bout : M=8192, N=1024 (f32 out)
    gemm_bt<1><<<dim3(64, 8), 256, 0, stream>>>((const u16*)ab, Woutb,
        nullptr, nullptr, nullptr, out, boutb);
}

// Round 6
// 213.050 us; speedup vs baseline: 1.1565x; 1.0506x over previous
//
#include <hip/hip_runtime.h>
#include <hip/hip_bf16.h>
#include <stdint.h>

typedef __hip_bfloat16 bf16;
typedef unsigned short u16;
typedef __attribute__((ext_vector_type(8))) short short8;
typedef __attribute__((ext_vector_type(4))) float f32x4;
typedef __attribute__((ext_vector_type(16))) float f32x16;
typedef __attribute__((ext_vector_type(4))) int int4v;

#define BATCH 8
#define SEQ   1024
#define DIM   1024
#define NHEAD 16
#define HD    64
#define SCALE 0.03125f               // DIM^-0.5 = 1/32 (exact)
#define C2    0.04508422f            // SCALE * log2(e)

static __device__ __forceinline__ f32x4 mfma_bf16(short8 a, short8 b, f32x4 c) {
    return __builtin_amdgcn_mfma_f32_16x16x32_bf16(a, b, c, 0, 0, 0);
}
static __device__ __forceinline__ f32x16 mfma32(short8 a, short8 b, f32x16 c) {
    return __builtin_amdgcn_mfma_f32_32x32x16_bf16(a, b, c, 0, 0, 0);
}
static __device__ __forceinline__ unsigned cvt_pk_bf16(float lo, float hi) {
    unsigned r;
    asm("v_cvt_pk_bf16_f32 %0, %1, %2" : "=v"(r) : "v"(lo), "v"(hi));
    return r;
}
static __device__ __forceinline__ float readlane_f(float v, int l) {
    return __builtin_bit_cast(float,
        __builtin_amdgcn_readlane(__builtin_bit_cast(int, v), l));
}
// async global->LDS, 16B per lane; LDS dest = wave-uniform base + lane*16
static __device__ __forceinline__ void gload16(const u16* g, u16* l) {
    __builtin_amdgcn_global_load_lds(
        (const __attribute__((address_space(1))) void*)g,
        (__attribute__((address_space(3))) void*)l, 16, 0, 0);
}

// ---------------------------------------------------------------------------
// Dtype detection (bit-pattern based, deterministic).
// ---------------------------------------------------------------------------
__global__ __launch_bounds__(256)
void detect_flags(const uint32_t* __restrict__ xw, const uint32_t* __restrict__ mw,
                  int* __restrict__ flags)
{
    __shared__ int cnt_bf16, cnt_gt1;
    if (threadIdx.x == 0) { cnt_bf16 = 0; cnt_gt1 = 0; }
    __syncthreads();
    const uint32_t w = xw[threadIdx.x];
    const int e = (int)((w >> 7) & 0xFFu);
    if (e >= 96 && e <= 159) atomicAdd(&cnt_bf16, 1);
    const uint32_t m = mw[threadIdx.x];
    if (m > 1u) atomicAdd(&cnt_gt1, 1);
    __syncthreads();
    if (threadIdx.x == 0) {
        flags[0] = (cnt_bf16 >= 192) ? 0 : 1;
        flags[1] = (cnt_gt1 > 0) ? 1 : 0;
    }
}

__global__ __launch_bounds__(256)
void convert_to_bf16(const void* __restrict__ src, u16* __restrict__ dst, int n,
                     const int* __restrict__ flags)
{
    const bool f32in = (flags[0] != 0);
    const int total = n >> 3;
    for (int i = blockIdx.x * blockDim.x + threadIdx.x; i < total;
         i += gridDim.x * blockDim.x) {
        if (f32in) {
            const float4 a = ((const float4*)src)[2 * i];
            const float4 b = ((const float4*)src)[2 * i + 1];
            short8 o;
            o[0] = (short)__builtin_bit_cast(u16, __float2bfloat16(a.x));
            o[1] = (short)__builtin_bit_cast(u16, __float2bfloat16(a.y));
            o[2] = (short)__builtin_bit_cast(u16, __float2bfloat16(a.z));
            o[3] = (short)__builtin_bit_cast(u16, __float2bfloat16(a.w));
            o[4] = (short)__builtin_bit_cast(u16, __float2bfloat16(b.x));
            o[5] = (short)__builtin_bit_cast(u16, __float2bfloat16(b.y));
            o[6] = (short)__builtin_bit_cast(u16, __float2bfloat16(b.z));
            o[7] = (short)__builtin_bit_cast(u16, __float2bfloat16(b.w));
            ((short8*)dst)[i] = o;
        } else {
            ((short8*)dst)[i] = ((const short8*)src)[i];
        }
    }
}

// mlx[b][0]=1 (pad-true), mlx[b][i]=mask[b][i-1]; mask64[b][t] = 64-bit tile mask
__global__ __launch_bounds__(1024)
void expand_mask(const void* __restrict__ mask, int* __restrict__ mlx,
                 unsigned long long* __restrict__ mask64,
                 const int* __restrict__ flags)
{
    const int b = blockIdx.x, i = threadIdx.x;
    int v;
    if (i == 0) v = 1;
    else if (flags[1]) v = (int)((const uint8_t*)mask)[b * (SEQ - 1) + i - 1];
    else               v = ((const int*)mask)[b * (SEQ - 1) + i - 1];
    v = v ? 1 : 0;
    mlx[b * SEQ + i] = v;
    const unsigned long long bal = __ballot(v);
    if ((i & 63) == 0) mask64[b * 16 + (i >> 6)] = bal;
}

// ---------------------------------------------------------------------------
// GEMM: C = A @ B^T, K=1024, bf16, m97 structure: global_load_lds width=16
// staging into linear [128][32] LDS (no pad), single barrier per K-step.
// 4 waves (2x2), wave 64x64 out.
// EPI 0: scatter into q/k [bh][n][64] and V TRANSPOSED [bh][d][n].
// EPI 1: C + bias -> f32 [M][DIM].
// ---------------------------------------------------------------------------
template<int EPI>
__global__ __launch_bounds__(256)
void gemm_bt(const u16* __restrict__ A, const u16* __restrict__ Bm,
             bf16* __restrict__ o0, bf16* __restrict__ o1, bf16* __restrict__ o2,
             float* __restrict__ fo, const u16* __restrict__ bias)
{
    constexpr int K = 1024;
    __shared__ u16 lA[2][128 * 32];
    __shared__ u16 lB[2][128 * 32];

    const int tid  = threadIdx.x;
    const int lane = tid & 63;
    const int w    = tid >> 6;
    const int wr   = w >> 1, wc = w & 1;
    const int l15  = lane & 15, l4 = lane >> 4;

    // staging geometry: wave w owns 1KB chunks c = 2w, 2w+1 of each tile.
    // chunk c covers rows c*16..c*16+15; lane l -> row c*16 + (l>>2),
    // col-chunk (l&3)*8 u16 (16B). LDS dest base is wave-uniform.
    const long atile = (long)blockIdx.x * 128;
    const long btile = (long)blockIdx.y * 128;
    const int  c0    = w * 2;
    const int  lrow  = lane >> 2;
    const int  lc8   = (lane & 3) * 8;
    const u16* gA0 = A  + (atile + c0 * 16 + lrow) * (long)K + lc8;
    const u16* gA1 = gA0 + 16L * K;
    const u16* gB0 = Bm + (btile + c0 * 16 + lrow) * (long)K + lc8;
    const u16* gB1 = gB0 + 16L * K;
    const int  ld0 = c0 * 512;           // u16 index of chunk base in LDS

    f32x4 acc[4][4];
    const f32x4 fz = {0.f, 0.f, 0.f, 0.f};
#pragma unroll
    for (int i = 0; i < 4; ++i)
#pragma unroll
        for (int j = 0; j < 4; ++j) acc[i][j] = fz;

#define STAGE_G(bufi, kt) do {                                    \
        gload16(gA0 + (kt) * 32, &lA[bufi][ld0]);                 \
        gload16(gA1 + (kt) * 32, &lA[bufi][ld0 + 512]);           \
        gload16(gB0 + (kt) * 32, &lB[bufi][ld0]);                 \
        gload16(gB1 + (kt) * 32, &lB[bufi][ld0 + 512]);           \
    } while (0)

    STAGE_G(0, 0);
    __syncthreads();                     // vmcnt(0) drain: tile 0 staged

    int cur = 0;
    constexpr int NT = K / 32;
#pragma unroll 1
    for (int kt = 0; kt < NT; ++kt) {
        if (kt + 1 < NT) STAGE_G(cur ^ 1, kt + 1);   // async into other buffer
        short8 af[4], bfr[4];
#pragma unroll
        for (int mt = 0; mt < 4; ++mt)
            af[mt] = *(const short8*)&lA[cur][(wr * 64 + mt * 16 + l15) * 32 + l4 * 8];
#pragma unroll
        for (int nt = 0; nt < 4; ++nt)
            bfr[nt] = *(const short8*)&lB[cur][(wc * 64 + nt * 16 + l15) * 32 + l4 * 8];
#pragma unroll
        for (int mt = 0; mt < 4; ++mt)
#pragma unroll
            for (int nt = 0; nt < 4; ++nt)
                acc[mt][nt] = mfma_bf16(af[mt], bfr[nt], acc[mt][nt]);
        __syncthreads();                 // reads done + next tile drained
        cur ^= 1;
    }
#undef STAGE_G

    // epilogue: C/D layout col = lane&15, row = (lane>>4)*4 + r  [m89/m91]
    const long ci0 = atile + wr * 64;
    const int  cj0 = (int)btile + wc * 64;
#pragma unroll
    for (int mt = 0; mt < 4; ++mt) {
#pragma unroll
        for (int nt = 0; nt < 4; ++nt) {
            const int j = cj0 + nt * 16 + l15;
#pragma unroll
            for (int r = 0; r < 4; ++r) {
                const long i = ci0 + mt * 16 + l4 * 4 + r;
                float vv = acc[mt][nt][r];
                if (EPI == 0) {
                    const int which = j >> 10;         // 0=q 1=k 2=v
                    const int h     = (j >> 6) & 15;
                    const int dd    = j & 63;
                    const long b    = i >> 10;
                    const long n    = i & 1023;
                    const long bhh  = b * NHEAD + h;
                    if (which == 0)
                        o0[(bhh * SEQ + n) * HD + dd] = __float2bfloat16(vv);
                    else if (which == 1)
                        o1[(bhh * SEQ + n) * HD + dd] = __float2bfloat16(vv);
                    else // V stored transposed: [bh][d][n]
                        o2[(bhh * HD + dd) * SEQ + n] = __float2bfloat16(vv);
                } else {
                    const u16 bw = bias[j];
                    vv += __bfloat162float(__builtin_bit_cast(bf16, bw));
                    fo[i * DIM + j] = vv;
                }
            }
        }
    }
}

// ---------------------------------------------------------------------------
// Flash attention, swapped-operand 32x32 form (m214 structure).
// Block = (b,h) x 128 q-rows; 4 waves x 32 q. KV tiles of 64.
// ---------------------------------------------------------------------------
__global__ __launch_bounds__(256)
void attn_fwd(const bf16* __restrict__ q, const bf16* __restrict__ k,
              const bf16* __restrict__ vt_g, const int* __restrict__ mlx,
              const unsigned long long* __restrict__ mask64,
              bf16* __restrict__ o)
{
    __shared__ u16 kl[64 * 72];        // K tile  [k in tile][d], +8 pad
    __shared__ u16 vl[64 * 72];        // V^T tile [d][k in tile], +8 pad

    const int tid  = threadIdx.x;
    const int lane = tid & 63;
    const int w    = tid >> 6;
    const int l31  = lane & 31;
    const int hi   = lane >> 5;
    const int bh   = blockIdx.x >> 3;
    const int qt   = blockIdx.x & 7;
    const int b    = bh >> 4;
    const int h    = bh & 15;

    const long base  = (long)bh * SEQ * HD;   // q,k: [bh][n][64]
    const long vbase = (long)bh * HD * SEQ;   // v^T: [bh][d][1024]

    const int qrow = qt * 128 + w * 32 + l31;

    short8 qf[4];                      // Q[qrow][s4*16 + hi*8 .. +7]
#pragma unroll
    for (int s4 = 0; s4 < 4; ++s4)
        qf[s4] = *(const short8*)(q + base + (long)qrow * HD + s4 * 16 + hi * 8);

    const int mi = mlx[b * SEQ + qrow];
    float mrun = mi ? -1e30f : 0.0f;
    float lrun = 0.0f;
    f32x16 oacc0, oacc1;
#pragma unroll
    for (int i = 0; i < 16; ++i) { oacc0[i] = 0.f; oacc1[i] = 0.f; }

    // staging: 256 threads, 2 x b128 each per tile (K and V^T)
    const int sr = tid >> 2, sc = tid & 3;
    short8 rk0 = *(const short8*)(k + base + (long)sr * HD + sc * 8);
    short8 rk1 = *(const short8*)(k + base + (long)sr * HD + 32 + sc * 8);
    short8 rv0 = *(const short8*)(vt_g + vbase + (long)sr * SEQ + sc * 8);
    short8 rv1 = *(const short8*)(vt_g + vbase + (long)sr * SEQ + 32 + sc * 8);

#pragma unroll 1
    for (int t = 0; t < 16; ++t) {
        __syncthreads();
        *(short8*)&kl[sr * 72 + sc * 8]      = rk0;
        *(short8*)&kl[sr * 72 + 32 + sc * 8] = rk1;
        *(short8*)&vl[sr * 72 + sc * 8]      = rv0;
        *(short8*)&vl[sr * 72 + 32 + sc * 8] = rv1;
        if (t < 15) {                  // T14: issue next-tile loads early
            const long kn = base + (long)((t + 1) * 64 + sr) * HD;
            rk0 = *(const short8*)(k + kn + sc * 8);
            rk1 = *(const short8*)(k + kn + 32 + sc * 8);
            const long vn = vbase + (long)sr * SEQ + (t + 1) * 64;
            rv0 = *(const short8*)(vt_g + vn + sc * 8);
            rv1 = *(const short8*)(vt_g + vn + 32 + sc * 8);
        }
        __syncthreads();

        // S^T = K . Q^T  (rows k, cols q)
        f32x16 s0, s1;
#pragma unroll
        for (int i = 0; i < 16; ++i) { s0[i] = 0.f; s1[i] = 0.f; }
#pragma unroll
        for (int s4 = 0; s4 < 4; ++s4) {
            const short8 kf0 = *(const short8*)&kl[l31 * 72 + s4 * 16 + hi * 8];
            const short8 kf1 = *(const short8*)&kl[(32 + l31) * 72 + s4 * 16 + hi * 8];
            s0 = mfma32(kf0, qf[s4], s0);
            s1 = mfma32(kf1, qf[s4], s1);
        }

        // row max
        float pm = s0[0];
#pragma unroll
        for (int i = 1; i < 16; ++i) pm = fmaxf(pm, s0[i]);
#pragma unroll
        for (int i = 0; i < 16; ++i) pm = fmaxf(pm, s1[i]);
        pm = fmaxf(pm, __shfl_xor(pm, 32));
        if (!mi) pm = -1e30f;

        if (__any(pm > mrun + 64.0f)) {   // T13 defer-max, THR=64 raw
            const float mnew = fmaxf(mrun, pm);
            const float fac  = exp2f((mrun - mnew) * C2);
            lrun *= fac;
            mrun  = mnew;
#pragma unroll
            for (int g = 0; g < 4; ++g)
#pragma unroll
                for (int j = 0; j < 4; ++j) {
                    const float f0 = readlane_f(fac, g * 8 + j);
                    const float f1 = readlane_f(fac, g * 8 + j + 4);
                    const float fv = hi ? f1 : f0;
                    oacc0[g * 4 + j] *= fv;
                    oacc1[g * 4 + j] *= fv;
                }
        }

        const float mb = mrun * C2;
        const unsigned long long mk = mask64[b * 16 + t];
        const uint32_t bk0 = (uint32_t)(mk >> (4 * hi));
        const uint32_t bk1 = (uint32_t)(mk >> (32 + 4 * hi));
        float rs = 0.0f;
#pragma unroll
        for (int i = 0; i < 16; ++i) {
            const int c = (i & 3) + 8 * (i >> 2);      // krow - 4*hi
            float p0 = exp2f(__builtin_fmaf(s0[i], C2, -mb));
            float p1 = exp2f(__builtin_fmaf(s1[i], C2, -mb));
            p0 = ((bk0 >> c) & 1u) ? p0 : 0.0f;
            p1 = ((bk1 >> c) & 1u) ? p1 : 0.0f;
            p0 = mi ? p0 : 1.0f;       // fully-masked row -> uniform
            p1 = mi ? p1 : 1.0f;
            s0[i] = p0; s1[i] = p1;
            rs += p0 + p1;
        }
        rs += __shfl_xor(rs, 32);
        lrun += rs;

        // P -> bf16 A-frags: pack lane-local pairs FIRST, then permlane32_swap
#pragma unroll
        for (int kt = 0; kt < 2; ++kt) {
            const f32x16* sp = kt ? &s1 : &s0;
#pragma unroll
            for (int ks = 0; ks < 2; ++ks) {
                unsigned w0 = cvt_pk_bf16((*sp)[8 * ks + 0], (*sp)[8 * ks + 1]);
                unsigned w1 = cvt_pk_bf16((*sp)[8 * ks + 2], (*sp)[8 * ks + 3]);
                unsigned w2 = cvt_pk_bf16((*sp)[8 * ks + 4], (*sp)[8 * ks + 5]);
                unsigned w3 = cvt_pk_bf16((*sp)[8 * ks + 6], (*sp)[8 * ks + 7]);
                asm volatile("v_permlane32_swap_b32 %0, %1" : "+v"(w0), "+v"(w2));
                asm volatile("v_permlane32_swap_b32 %0, %1" : "+v"(w1), "+v"(w3));
                const short8 pa = __builtin_bit_cast(short8,
                    (int4v){(int)w0, (int)w1, (int)w2, (int)w3});
                const int koff = kt * 32 + ks * 16 + hi * 8;
                const short8 vf0 = *(const short8*)&vl[l31 * 72 + koff];
                const short8 vf1 = *(const short8*)&vl[(32 + l31) * 72 + koff];
                oacc0 = mfma32(pa, vf0, oacc0);
                oacc1 = mfma32(pa, vf1, oacc1);
            }
        }
    }

    // epilogue: O[q][d] / l
    const float linv = 1.0f / lrun;
#pragma unroll
    for (int g = 0; g < 4; ++g)
#pragma unroll
        for (int j = 0; j < 4; ++j) {
            const float f0 = readlane_f(linv, g * 8 + j);
            const float f1 = readlane_f(linv, g * 8 + j + 4);
            const float lv = hi ? f1 : f0;
            const int qg = qt * 128 + w * 32 + g * 8 + j + 4 * hi;
            const long oaddr = ((long)(b * SEQ + qg)) * DIM + h * HD;
            o[oaddr + l31]      = __float2bfloat16(oacc0[g * 4 + j] * lv);
            o[oaddr + 32 + l31] = __float2bfloat16(oacc1[g * 4 + j] * lv);
        }
}

// ---------------------------------------------------------------------------
extern "C" void kernel_launch(void* const* d_in, const int* in_sizes, int n_in,
                              void* d_out, int out_size, void* d_ws, size_t ws_size,
                              hipStream_t stream)
{
    (void)in_sizes; (void)n_in; (void)out_size; (void)ws_size;
    const void* x    = d_in[0];
    const void* mask = d_in[1];
    const void* Wqkv = d_in[2];
    const void* Wout = d_in[3];
    const void* bout = d_in[4];
    float* out = (float*)d_out;

    const size_t nX    = (size_t)BATCH * SEQ * DIM;
    const size_t nWqkv = (size_t)3 * DIM * DIM;
    const size_t nWout = (size_t)DIM * DIM;
    const size_t nBout = DIM;
    const size_t per   = (size_t)BATCH * NHEAD * SEQ * HD;

    char* wp = (char*)d_ws;
    int* flags = (int*)wp;                      wp += 256;
    u16* xb    = (u16*)wp;                      wp += nX * 2;   // reused as ab
    u16* Wqkvb = (u16*)wp;                      wp += nWqkv * 2;
    u16* Woutb = (u16*)wp;                      wp += nWout * 2;
    u16* boutb = (u16*)wp;                      wp += nBout * 2;
    int* mlx   = (int*)wp;                      wp += BATCH * SEQ * 4;
    unsigned long long* m64 = (unsigned long long*)wp; wp += BATCH * 16 * 8;
    u16* qb    = (u16*)wp;                      wp += per * 2;
    u16* kb    = (u16*)wp;                      wp += per * 2;
    u16* vb    = (u16*)wp;                      wp += per * 2;

    detect_flags<<<1, 256, 0, stream>>>((const uint32_t*)x, (const uint32_t*)mask, flags);
    convert_to_bf16<<<2048, 256, 0, stream>>>(x,    xb,    (int)nX,    flags);
    convert_to_bf16<<<1536, 256, 0, stream>>>(Wqkv, Wqkvb, (int)nWqkv, flags);
    convert_to_bf16<<<512,  256, 0, stream>>>(Wout, Woutb, (int)nWout, flags);
    convert_to_bf16<<<1,    256, 0, stream>>>(bout, boutb, (int)nBout, flags);
    expand_mask<<<BATCH, 1024, 0, stream>>>(mask, mlx, m64, flags);

    // qkv = x @ Wqkv^T : M=8192, N=3072 (V scattered transposed)
    gemm_bt<0><<<dim3(64, 24), 256, 0, stream>>>(xb, Wqkvb,
        (bf16*)qb, (bf16*)kb, (bf16*)vb, nullptr, nullptr);
    // attention -> ab (reuses xb region)
    bf16* ab = (bf16*)xb;
    attn_fwd<<<dim3(BATCH * NHEAD * 8), 256, 0, stream>>>(
        (const bf16*)qb, (const bf16*)kb, (const bf16*)vb, mlx, m64, ab);
    // out = attn @ Wout^T + bout : M=8192, N=1024 (f32 out)
    gemm_bt<1><<<dim3(64, 8), 256, 0, stream>>>((const u16*)ab, Woutb,
        nullptr, nullptr, nullptr, out, boutb);
}

// Round 7
// 208.201 us; speedup vs baseline: 1.1835x; 1.0233x over previous
//
#include <hip/hip_runtime.h>
#include <hip/hip_bf16.h>
#include <stdint.h>

typedef __hip_bfloat16 bf16;
typedef unsigned short u16;
typedef __attribute__((ext_vector_type(8))) short short8;
typedef __attribute__((ext_vector_type(4))) float f32x4;
typedef __attribute__((ext_vector_type(16))) float f32x16;
typedef __attribute__((ext_vector_type(4))) int int4v;

#define BATCH 8
#define SEQ   1024
#define DIM   1024
#define NHEAD 16
#define HD    64
#define SCALE 0.03125f               // DIM^-0.5 = 1/32 (exact)
#define C2    0.04508422f            // SCALE * log2(e)

static __device__ __forceinline__ f32x4 mfma_bf16(short8 a, short8 b, f32x4 c) {
    return __builtin_amdgcn_mfma_f32_16x16x32_bf16(a, b, c, 0, 0, 0);
}
static __device__ __forceinline__ f32x16 mfma32(short8 a, short8 b, f32x16 c) {
    return __builtin_amdgcn_mfma_f32_32x32x16_bf16(a, b, c, 0, 0, 0);
}
static __device__ __forceinline__ unsigned cvt_pk_bf16(float lo, float hi) {
    unsigned r;
    asm("v_cvt_pk_bf16_f32 %0, %1, %2" : "=v"(r) : "v"(lo), "v"(hi));
    return r;
}
static __device__ __forceinline__ float readlane_f(float v, int l) {
    return __builtin_bit_cast(float,
        __builtin_amdgcn_readlane(__builtin_bit_cast(int, v), l));
}
// async global->LDS, 16B per lane; LDS dest = wave-uniform base + lane*16
static __device__ __forceinline__ void gload16(const u16* g, u16* l) {
    __builtin_amdgcn_global_load_lds(
        (const __attribute__((address_space(1))) void*)g,
        (__attribute__((address_space(3))) void*)l, 16, 0, 0);
}

// ---------------------------------------------------------------------------
// Dtype detection (bit-pattern based, deterministic).
// ---------------------------------------------------------------------------
__global__ __launch_bounds__(256)
void detect_flags(const uint32_t* __restrict__ xw, const uint32_t* __restrict__ mw,
                  int* __restrict__ flags)
{
    __shared__ int cnt_bf16, cnt_gt1;
    if (threadIdx.x == 0) { cnt_bf16 = 0; cnt_gt1 = 0; }
    __syncthreads();
    const uint32_t w = xw[threadIdx.x];
    const int e = (int)((w >> 7) & 0xFFu);
    if (e >= 96 && e <= 159) atomicAdd(&cnt_bf16, 1);
    const uint32_t m = mw[threadIdx.x];
    if (m > 1u) atomicAdd(&cnt_gt1, 1);
    __syncthreads();
    if (threadIdx.x == 0) {
        flags[0] = (cnt_bf16 >= 192) ? 0 : 1;
        flags[1] = (cnt_gt1 > 0) ? 1 : 0;
    }
}

__global__ __launch_bounds__(256)
void convert_to_bf16(const void* __restrict__ src, u16* __restrict__ dst, int n,
                     const int* __restrict__ flags)
{
    const bool f32in = (flags[0] != 0);
    const int total = n >> 3;
    for (int i = blockIdx.x * blockDim.x + threadIdx.x; i < total;
         i += gridDim.x * blockDim.x) {
        if (f32in) {
            const float4 a = ((const float4*)src)[2 * i];
            const float4 b = ((const float4*)src)[2 * i + 1];
            short8 o;
            o[0] = (short)__builtin_bit_cast(u16, __float2bfloat16(a.x));
            o[1] = (short)__builtin_bit_cast(u16, __float2bfloat16(a.y));
            o[2] = (short)__builtin_bit_cast(u16, __float2bfloat16(a.z));
            o[3] = (short)__builtin_bit_cast(u16, __float2bfloat16(a.w));
            o[4] = (short)__builtin_bit_cast(u16, __float2bfloat16(b.x));
            o[5] = (short)__builtin_bit_cast(u16, __float2bfloat16(b.y));
            o[6] = (short)__builtin_bit_cast(u16, __float2bfloat16(b.z));
            o[7] = (short)__builtin_bit_cast(u16, __float2bfloat16(b.w));
            ((short8*)dst)[i] = o;
        } else {
            ((short8*)dst)[i] = ((const short8*)src)[i];
        }
    }
}

// mlx[b][0]=1 (pad-true), mlx[b][i]=mask[b][i-1]; mask64[b][t] = 64-bit tile mask
__global__ __launch_bounds__(1024)
void expand_mask(const void* __restrict__ mask, int* __restrict__ mlx,
                 unsigned long long* __restrict__ mask64,
                 const int* __restrict__ flags)
{
    const int b = blockIdx.x, i = threadIdx.x;
    int v;
    if (i == 0) v = 1;
    else if (flags[1]) v = (int)((const uint8_t*)mask)[b * (SEQ - 1) + i - 1];
    else               v = ((const int*)mask)[b * (SEQ - 1) + i - 1];
    v = v ? 1 : 0;
    mlx[b * SEQ + i] = v;
    const unsigned long long bal = __ballot(v);
    if ((i & 63) == 0) mask64[b * 16 + (i >> 6)] = bal;
}

// ---------------------------------------------------------------------------
// GEMM: C = A @ B^T, K=1024, bf16, m97 structure: global_load_lds width=16
// staging into linear [128][32] LDS, single barrier per K-step.
// ---------------------------------------------------------------------------
template<int EPI>
__global__ __launch_bounds__(256)
void gemm_bt(const u16* __restrict__ A, const u16* __restrict__ Bm,
             bf16* __restrict__ o0, bf16* __restrict__ o1, bf16* __restrict__ o2,
             float* __restrict__ fo, const u16* __restrict__ bias)
{
    constexpr int K = 1024;
    __shared__ u16 lA[2][128 * 32];
    __shared__ u16 lB[2][128 * 32];

    const int tid  = threadIdx.x;
    const int lane = tid & 63;
    const int w    = tid >> 6;
    const int wr   = w >> 1, wc = w & 1;
    const int l15  = lane & 15, l4 = lane >> 4;

    const long atile = (long)blockIdx.x * 128;
    const long btile = (long)blockIdx.y * 128;
    const int  c0    = w * 2;
    const int  lrow  = lane >> 2;
    const int  lc8   = (lane & 3) * 8;
    const u16* gA0 = A  + (atile + c0 * 16 + lrow) * (long)K + lc8;
    const u16* gA1 = gA0 + 16L * K;
    const u16* gB0 = Bm + (btile + c0 * 16 + lrow) * (long)K + lc8;
    const u16* gB1 = gB0 + 16L * K;
    const int  ld0 = c0 * 512;

    f32x4 acc[4][4];
    const f32x4 fz = {0.f, 0.f, 0.f, 0.f};
#pragma unroll
    for (int i = 0; i < 4; ++i)
#pragma unroll
        for (int j = 0; j < 4; ++j) acc[i][j] = fz;

#define STAGE_G(bufi, kt) do {                                    \
        gload16(gA0 + (kt) * 32, &lA[bufi][ld0]);                 \
        gload16(gA1 + (kt) * 32, &lA[bufi][ld0 + 512]);           \
        gload16(gB0 + (kt) * 32, &lB[bufi][ld0]);                 \
        gload16(gB1 + (kt) * 32, &lB[bufi][ld0 + 512]);           \
    } while (0)

    STAGE_G(0, 0);
    __syncthreads();

    int cur = 0;
    constexpr int NT = K / 32;
#pragma unroll 1
    for (int kt = 0; kt < NT; ++kt) {
        if (kt + 1 < NT) STAGE_G(cur ^ 1, kt + 1);
        short8 af[4], bfr[4];
#pragma unroll
        for (int mt = 0; mt < 4; ++mt)
            af[mt] = *(const short8*)&lA[cur][(wr * 64 + mt * 16 + l15) * 32 + l4 * 8];
#pragma unroll
        for (int nt = 0; nt < 4; ++nt)
            bfr[nt] = *(const short8*)&lB[cur][(wc * 64 + nt * 16 + l15) * 32 + l4 * 8];
#pragma unroll
        for (int mt = 0; mt < 4; ++mt)
#pragma unroll
            for (int nt = 0; nt < 4; ++nt)
                acc[mt][nt] = mfma_bf16(af[mt], bfr[nt], acc[mt][nt]);
        __syncthreads();
        cur ^= 1;
    }
#undef STAGE_G

    const long ci0 = atile + wr * 64;
    const int  cj0 = (int)btile + wc * 64;
#pragma unroll
    for (int mt = 0; mt < 4; ++mt) {
#pragma unroll
        for (int nt = 0; nt < 4; ++nt) {
            const int j = cj0 + nt * 16 + l15;
#pragma unroll
            for (int r = 0; r < 4; ++r) {
                const long i = ci0 + mt * 16 + l4 * 4 + r;
                float vv = acc[mt][nt][r];
                if (EPI == 0) {
                    const int which = j >> 10;         // 0=q 1=k 2=v
                    const int h     = (j >> 6) & 15;
                    const int dd    = j & 63;
                    const long b    = i >> 10;
                    const long n    = i & 1023;
                    const long bhh  = b * NHEAD + h;
                    if (which == 0)
                        o0[(bhh * SEQ + n) * HD + dd] = __float2bfloat16(vv);
                    else if (which == 1)
                        o1[(bhh * SEQ + n) * HD + dd] = __float2bfloat16(vv);
                    else // V stored transposed: [bh][d][n]
                        o2[(bhh * HD + dd) * SEQ + n] = __float2bfloat16(vv);
                } else {
                    const u16 bw = bias[j];
                    vv += __bfloat162float(__builtin_bit_cast(bf16, bw));
                    fo[i * DIM + j] = vv;
                }
            }
        }
    }
}

// ---------------------------------------------------------------------------
// Flash attention, swapped-operand 32x32 form.
// Mask -> rank-1 MFMA bias (no per-element VALU); Σp -> ones-column MFMA
// (lrun in accumulator layout, no readlane epilogue); mi rows via per-lane
// (c2l, mbl) so p==1 with zero per-element cost.
// ---------------------------------------------------------------------------
__global__ __launch_bounds__(256)
void attn_fwd(const bf16* __restrict__ q, const bf16* __restrict__ k,
              const bf16* __restrict__ vt_g, const int* __restrict__ mlx,
              const unsigned long long* __restrict__ mask64,
              bf16* __restrict__ o)
{
    __shared__ u16 kl[64 * 72];        // K tile  [k in tile][d], +8 pad
    __shared__ u16 vl[64 * 72];        // V^T tile [d][k in tile], +8 pad

    const int tid  = threadIdx.x;
    const int lane = tid & 63;
    const int w    = tid >> 6;
    const int l31  = lane & 31;
    const int hi   = lane >> 5;
    const int bh   = blockIdx.x >> 3;
    const int qt   = blockIdx.x & 7;
    const int b    = bh >> 4;
    const int h    = bh & 15;

    const long base  = (long)bh * SEQ * HD;   // q,k: [bh][n][64]
    const long vbase = (long)bh * HD * SEQ;   // v^T: [bh][d][1024]

    const int qrow = qt * 128 + w * 32 + l31;

    short8 qf[4];
#pragma unroll
    for (int s4 = 0; s4 < 4; ++s4)
        qf[s4] = *(const short8*)(q + base + (long)qrow * HD + s4 * 16 + hi * 8);

    const int mi = mlx[b * SEQ + qrow];
    const float c2l = mi ? C2 : 0.0f;         // mi==0: p = exp2(0) = 1 always
    float mrun = mi ? -1e30f : 0.0f;
    f32x16 oacc0, oacc1, oaccS;
#pragma unroll
    for (int i = 0; i < 16; ++i) { oacc0[i] = 0.f; oacc1[i] = 0.f; oaccS[i] = 0.f; }

    // constant MFMA fragments
    const u16 NEGW = __builtin_bit_cast(u16, __float2bfloat16(-1e30f));
    const short8 vfB = __builtin_bit_cast(short8,            // ones at kk=0
        (int4v){hi ? 0 : 0x3F80, 0, 0, 0});
    const short8 vfS = __builtin_bit_cast(short8,            // all-ones column
        (int4v){0x3F803F80, 0x3F803F80, 0x3F803F80, 0x3F803F80});

    // staging: 256 threads, 2 x b128 each per tile (K and V^T)
    const int sr = tid >> 2, sc = tid & 3;
    short8 rk0 = *(const short8*)(k + base + (long)sr * HD + sc * 8);
    short8 rk1 = *(const short8*)(k + base + (long)sr * HD + 32 + sc * 8);
    short8 rv0 = *(const short8*)(vt_g + vbase + (long)sr * SEQ + sc * 8);
    short8 rv1 = *(const short8*)(vt_g + vbase + (long)sr * SEQ + 32 + sc * 8);

#pragma unroll 1
    for (int t = 0; t < 16; ++t) {
        __syncthreads();
        *(short8*)&kl[sr * 72 + sc * 8]      = rk0;
        *(short8*)&kl[sr * 72 + 32 + sc * 8] = rk1;
        *(short8*)&vl[sr * 72 + sc * 8]      = rv0;
        *(short8*)&vl[sr * 72 + 32 + sc * 8] = rv1;
        if (t < 15) {                  // T14: issue next-tile loads early
            const long kn = base + (long)((t + 1) * 64 + sr) * HD;
            rk0 = *(const short8*)(k + kn + sc * 8);
            rk1 = *(const short8*)(k + kn + 32 + sc * 8);
            const long vn = vbase + (long)sr * SEQ + (t + 1) * 64;
            rv0 = *(const short8*)(vt_g + vn + sc * 8);
            rv1 = *(const short8*)(vt_g + vn + 32 + sc * 8);
        }
        __syncthreads();

        // mask bias A-frags: bias[k] at kk=0; k = l31 (s0) / 32+l31 (s1)
        const unsigned long long mk = mask64[b * 16 + t];
        const unsigned bit0 = (unsigned)(mk >> l31) & 1u;
        const unsigned bit1 = (unsigned)(mk >> (32 + l31)) & 1u;
        const short8 paB0 = __builtin_bit_cast(short8,
            (int4v){(hi == 0 && !bit0) ? (int)(unsigned)NEGW : 0, 0, 0, 0});
        const short8 paB1 = __builtin_bit_cast(short8,
            (int4v){(hi == 0 && !bit1) ? (int)(unsigned)NEGW : 0, 0, 0, 0});

        // S^T = K . Q^T + rank-1 mask bias
        f32x16 s0, s1;
#pragma unroll
        for (int i = 0; i < 16; ++i) { s0[i] = 0.f; s1[i] = 0.f; }
        s0 = mfma32(paB0, vfB, s0);
        s1 = mfma32(paB1, vfB, s1);
#pragma unroll
        for (int s4 = 0; s4 < 4; ++s4) {
            const short8 kf0 = *(const short8*)&kl[l31 * 72 + s4 * 16 + hi * 8];
            const short8 kf1 = *(const short8*)&kl[(32 + l31) * 72 + s4 * 16 + hi * 8];
            s0 = mfma32(kf0, qf[s4], s0);
            s1 = mfma32(kf1, qf[s4], s1);
        }

        // row max (raw; masked -1e30 entries lose)
        float pm = s0[0];
#pragma unroll
        for (int i = 1; i < 16; ++i) pm = fmaxf(pm, s0[i]);
#pragma unroll
        for (int i = 0; i < 16; ++i) pm = fmaxf(pm, s1[i]);
        pm = fmaxf(pm, __shfl_xor(pm, 32));
        if (!mi) pm = -1e30f;

        if (__any(pm > mrun + 64.0f)) {   // T13 defer-max, THR=64 raw
            const float mnew = fmaxf(mrun, pm);
            const float fac  = exp2f((mrun - mnew) * C2);
            mrun = mnew;
#pragma unroll
            for (int g = 0; g < 4; ++g)
#pragma unroll
                for (int j = 0; j < 4; ++j) {
                    const float f0 = readlane_f(fac, g * 8 + j);
                    const float f1 = readlane_f(fac, g * 8 + j + 4);
                    const float fv = hi ? f1 : f0;
                    oacc0[g * 4 + j] *= fv;
                    oacc1[g * 4 + j] *= fv;
                    oaccS[g * 4 + j] *= fv;
                }
        }

        const float mbl = -mrun * c2l;    // mi==0: 0

        // fused exp + pack + PV + Σp  (pack: lane-local pk, permlane routes)
#pragma unroll
        for (int kt = 0; kt < 2; ++kt) {
            const f32x16* sp = kt ? &s1 : &s0;
#pragma unroll
            for (int ks = 0; ks < 2; ++ks) {
                float p[8];
#pragma unroll
                for (int e = 0; e < 8; ++e)
                    p[e] = exp2f(__builtin_fmaf((*sp)[8 * ks + e], c2l, mbl));
                unsigned w0 = cvt_pk_bf16(p[0], p[1]);
                unsigned w1 = cvt_pk_bf16(p[2], p[3]);
                unsigned w2 = cvt_pk_bf16(p[4], p[5]);
                unsigned w3 = cvt_pk_bf16(p[6], p[7]);
                asm volatile("v_permlane32_swap_b32 %0, %1" : "+v"(w0), "+v"(w2));
                asm volatile("v_permlane32_swap_b32 %0, %1" : "+v"(w1), "+v"(w3));
                const short8 pa = __builtin_bit_cast(short8,
                    (int4v){(int)w0, (int)w1, (int)w2, (int)w3});
                const int koff = kt * 32 + ks * 16 + hi * 8;
                const short8 vf0 = *(const short8*)&vl[l31 * 72 + koff];
                const short8 vf1 = *(const short8*)&vl[(32 + l31) * 72 + koff];
                oacc0 = mfma32(pa, vf0, oacc0);
                oacc1 = mfma32(pa, vf1, oacc1);
                oaccS = mfma32(pa, vfS, oaccS);   // row-sum column
            }
        }
    }

    // epilogue: O[q][d] * rcp(Σp) — Σp already in accumulator layout
#pragma unroll
    for (int g = 0; g < 4; ++g)
#pragma unroll
        for (int j = 0; j < 4; ++j) {
            const int idx = g * 4 + j;
            const float lv = __builtin_amdgcn_rcpf(oaccS[idx]);
            const int qg = qt * 128 + w * 32 + g * 8 + j + 4 * hi;
            const long oaddr = ((long)(b * SEQ + qg)) * DIM + h * HD;
            o[oaddr + l31]      = __float2bfloat16(oacc0[idx] * lv);
            o[oaddr + 32 + l31] = __float2bfloat16(oacc1[idx] * lv);
        }
}

// ---------------------------------------------------------------------------
extern "C" void kernel_launch(void* const* d_in, const int* in_sizes, int n_in,
                              void* d_out, int out_size, void* d_ws, size_t ws_size,
                              hipStream_t stream)
{
    (void)in_sizes; (void)n_in; (void)out_size; (void)ws_size;
    const void* x    = d_in[0];
    const void* mask = d_in[1];
    const void* Wqkv = d_in[2];
    const void* Wout = d_in[3];
    const void* bout = d_in[4];
    float* out = (float*)d_out;

    const size_t nX    = (size_t)BATCH * SEQ * DIM;
    const size_t nWqkv = (size_t)3 * DIM * DIM;
    const size_t nWout = (size_t)DIM * DIM;
    const size_t nBout = DIM;
    const size_t per   = (size_t)BATCH * NHEAD * SEQ * HD;

    char* wp = (char*)d_ws;
    int* flags = (int*)wp;                      wp += 256;
    u16* xb    = (u16*)wp;                      wp += nX * 2;   // reused as ab
    u16* Wqkvb = (u16*)wp;                      wp += nWqkv * 2;
    u16* Woutb = (u16*)wp;                      wp += nWout * 2;
    u16* boutb = (u16*)wp;                      wp += nBout * 2;
    int* mlx   = (int*)wp;                      wp += BATCH * SEQ * 4;
    unsigned long long* m64 = (unsigned long long*)wp; wp += BATCH * 16 * 8;
    u16* qb    = (u16*)wp;                      wp += per * 2;
    u16* kb    = (u16*)wp;                      wp += per * 2;
    u16* vb    = (u16*)wp;                      wp += per * 2;

    detect_flags<<<1, 256, 0, stream>>>((const uint32_t*)x, (const uint32_t*)mask, flags);
    convert_to_bf16<<<2048, 256, 0, stream>>>(x,    xb,    (int)nX,    flags);
    convert_to_bf16<<<1536, 256, 0, stream>>>(Wqkv, Wqkvb, (int)nWqkv, flags);
    convert_to_bf16<<<512,  256, 0, stream>>>(Wout, Woutb, (int)nWout, flags);
    convert_to_bf16<<<1,    256, 0, stream>>>(bout, boutb, (int)nBout, flags);
    expand_mask<<<BATCH, 1024, 0, stream>>>(mask, mlx, m64, flags);

    // qkv = x @ Wqkv^T : M=8192, N=3072 (V scattered transposed)
    gemm_bt<0><<<dim3(64, 24), 256, 0, stream>>>(xb, Wqkvb,
        (bf16*)qb, (bf16*)kb, (bf16*)vb, nullptr, nullptr);
    // attention -> ab (reuses xb region)
    bf16* ab = (bf16*)xb;
    attn_fwd<<<dim3(BATCH * NHEAD * 8), 256, 0, stream>>>(
        (const bf16*)qb, (const bf16*)kb, (const bf16*)vb, mlx, m64, ab);
    // out = attn @ Wout^T + bout : M=8192, N=1024 (f32 out)
    gemm_bt<1><<<dim3(64, 8), 256, 0, stream>>>((const u16*)ab, Woutb,
        nullptr, nullptr, nullptr, out, boutb);
}